// Round 8
// baseline (2490.029 us; speedup 1.0000x reference)
//
#include <hip/hip_runtime.h>
#include <math.h>

// MoDGMMFeatureModel, numpy-fp32-bit-exact (frozen op orders, proven round 3):
//  - sgemm: acc=0, sequential-k __builtin_fmaf, bias added AFTER (own rounding)
//  - LN mean/var: numpy pairwise 8-accumulator pattern
//  - elementwise: contract(off), left-assoc as written
//  - mod: fmodf + conditional += 2pi
// Round 8: FULLY-STATIC monolith. No LDS anywhere: every k-loop fully
// unrolled so activations live in registers with static indices and weight
// addresses are compile-time constants -> pure s_load + v_fmac stream.
// Removing ds_read from the k-loops un-poisons lgkmcnt (SMEM is out-of-order:
// any DS+SMEM mix forces lgkmcnt(0) full drains every k — round 3's 43.5%
// VALUBusy cap). Compiler can now pipeline the next weight batch's s_load
// under the current FMA burst. 2 waves/SIMD (~225 live regs), no barriers.

constexpr int N_PTS = 1000000;
constexpr int GW = 64;
constexpr int FDIM = 32;
constexpr int DIN = 34;
constexpr int NH1 = 128;
constexpr int NH2 = 64;
constexpr int NOUT = 48;
constexpr int NC = 8;
constexpr int BLK = 256;

// numpy pairwise_sum (8-accumulator pattern), register arrays, static indices
template<int N>
__device__ __forceinline__ float np_pairwise(const float* x) {
#pragma clang fp contract(off)
    float r[8];
#pragma unroll
    for (int j = 0; j < 8; ++j) r[j] = x[j];
#pragma unroll
    for (int m = 1; m < N / 8; ++m)
#pragma unroll
        for (int j = 0; j < 8; ++j) r[j] = r[j] + x[8 * m + j];
    return ((r[0] + r[1]) + (r[2] + r[3])) + ((r[4] + r[5]) + (r[6] + r[7]));
}

template<int N>
__device__ __forceinline__ float np_pairwise_sq(const float* x, float mu) {
#pragma clang fp contract(off)
    float r[8];
#pragma unroll
    for (int j = 0; j < 8; ++j) { const float d = x[j] - mu; r[j] = d * d; }
#pragma unroll
    for (int m = 1; m < N / 8; ++m)
#pragma unroll
        for (int j = 0; j < 8; ++j) {
            const float d = x[8 * m + j] - mu;
            r[j] = r[j] + d * d;
        }
    return ((r[0] + r[1]) + (r[2] + r[3])) + ((r[4] + r[5]) + (r[6] + r[7]));
}

__global__ __launch_bounds__(BLK, 2) void modgmm_np32_static(
    const float* __restrict__ coords,
    const float* __restrict__ grid,
    const float* __restrict__ W1, const float* __restrict__ b1,
    const float* __restrict__ g1, const float* __restrict__ be1,
    const float* __restrict__ W2, const float* __restrict__ b2,
    const float* __restrict__ g2, const float* __restrict__ be2,
    const float* __restrict__ W3, const float* __restrict__ b3,
    float* __restrict__ gmm_out, float* __restrict__ coords_out)
{
#pragma clang fp contract(off)
    const int i = blockIdx.x * BLK + threadIdx.x;
    if (i >= N_PTS) return;   // no barriers anywhere: safe

    const float2 c2 = reinterpret_cast<const float2*>(coords)[i];
    const float cx = c2.x, cy = c2.y;

    // ---- bilinear gather, numpy op order (identical to round 3) ----
    const float x = cx * 63.0f;
    const float y = cy * 63.0f;
    int x0 = (int)floorf(x); x0 = x0 < 0 ? 0 : (x0 > 62 ? 62 : x0);
    int y0 = (int)floorf(y); y0 = y0 < 0 ? 0 : (y0 > 62 ? 62 : y0);
    const float dx = x - (float)x0;
    const float dy = y - (float)y0;
    const float omdx = 1.0f - dx;
    const float omdy = 1.0f - dy;
    const float w00 = omdx * omdy;
    const float w01 = omdx * dy;
    const float w10 = dx * omdy;
    const float w11 = dx * dy;
    const float* __restrict__ gp = grid + (y0 * GW + x0) * FDIM;

    // feat vector fully in registers, static indices
    float f[DIN];
    f[0] = cx; f[1] = cy;
#pragma unroll
    for (int k = 0; k < FDIM; ++k) {
        const float t0 = w00 * gp[k];
        const float t1 = w01 * gp[GW * FDIM + k];
        const float t2 = w10 * gp[FDIM + k];
        const float t3 = w11 * gp[GW * FDIM + FDIM + k];
        f[2 + k] = ((t0 + t1) + t2) + t3;
    }

    // ---- layer 1: 34 -> 128, fully unrolled, weights via s_load ----
    float h[NH1];
#pragma unroll
    for (int j = 0; j < NH1; ++j) h[j] = 0.0f;
#pragma unroll
    for (int k = 0; k < DIN; ++k) {
        const float hv = f[k];
        const float* __restrict__ wr = W1 + k * NH1;
#pragma unroll
        for (int j = 0; j < NH1; ++j) h[j] = __builtin_fmaf(hv, wr[j], h[j]);
    }
#pragma unroll
    for (int j = 0; j < NH1; ++j) h[j] = fmaxf(h[j] + b1[j], 0.0f);

    // ---- layernorm 1 ----
    {
        const float mu = np_pairwise<NH1>(h) / 128.0f;
        const float var = np_pairwise_sq<NH1>(h, mu) / 128.0f;
        const float rs = 1.0f / sqrtf(var + 1e-5f);
#pragma unroll
        for (int j = 0; j < NH1; ++j)
            h[j] = ((h[j] - mu) * rs) * g1[j] + be1[j];
    }

    // ---- layer 2: 128 -> 64, fully unrolled (h[k] static register reads) ----
    float h2[NH2];
#pragma unroll
    for (int j = 0; j < NH2; ++j) h2[j] = 0.0f;
#pragma unroll
    for (int k = 0; k < NH1; ++k) {
        const float hv = h[k];
        const float* __restrict__ wr = W2 + k * NH2;
#pragma unroll
        for (int j = 0; j < NH2; ++j) h2[j] = __builtin_fmaf(hv, wr[j], h2[j]);
    }
#pragma unroll
    for (int j = 0; j < NH2; ++j) h2[j] = fmaxf(h2[j] + b2[j], 0.0f);

    // ---- layernorm 2 ----
    {
        const float mu = np_pairwise<NH2>(h2) / 64.0f;
        const float var = np_pairwise_sq<NH2>(h2, mu) / 64.0f;
        const float rs = 1.0f / sqrtf(var + 1e-5f);
#pragma unroll
        for (int j = 0; j < NH2; ++j)
            h2[j] = ((h2[j] - mu) * rs) * g2[j] + be2[j];
    }

    // ---- layer 3: 64 -> 48, fully unrolled ----
    float o[NOUT];
#pragma unroll
    for (int j = 0; j < NOUT; ++j) o[j] = 0.0f;
#pragma unroll
    for (int k = 0; k < NH2; ++k) {
        const float hv = h2[k];
        const float* __restrict__ wr = W3 + k * NOUT;
#pragma unroll
        for (int j = 0; j < NOUT; ++j) o[j] = __builtin_fmaf(hv, wr[j], o[j]);
    }
#pragma unroll
    for (int j = 0; j < NOUT; ++j) o[j] = o[j] + b3[j];

    // ---- GMM postprocess (identical to round 3) ----
    const float TPf = 6.28318530717958647692f;
    float res[NOUT];
    float m = o[0];
#pragma unroll
    for (int c = 1; c < NC; ++c) m = fmaxf(m, o[6 * c]);
    float e[NC];
#pragma unroll
    for (int c = 0; c < NC; ++c) e[c] = expf(o[6 * c] - m);
    const float esum = ((e[0] + e[1]) + (e[2] + e[3])) + ((e[4] + e[5]) + (e[6] + e[7]));
#pragma unroll
    for (int c = 0; c < NC; ++c) {
        res[6 * c + 0] = e[c] / esum;
        res[6 * c + 1] = fmaxf(o[6 * c + 1], 0.0f);
        float a = fmodf(o[6 * c + 2], TPf);
        if (a < 0.0f) a += TPf;
        res[6 * c + 2] = a;
        res[6 * c + 3] = expf(fminf(fmaxf(o[6 * c + 3], -10.0f), 10.0f));
        res[6 * c + 4] = expf(fminf(fmaxf(o[6 * c + 4], -10.0f), 10.0f));
        res[6 * c + 5] = 0.99f * tanhf(o[6 * c + 5]);
    }

    // ---- stores (coalesced, 192 B contiguous per thread) ----
    float4* og = reinterpret_cast<float4*>(gmm_out + (size_t)i * NOUT);
#pragma unroll
    for (int q = 0; q < NOUT / 4; ++q)
        og[q] = make_float4(res[4 * q + 0], res[4 * q + 1], res[4 * q + 2], res[4 * q + 3]);
    reinterpret_cast<float2*>(coords_out)[i] = make_float2(cx, cy);
}

extern "C" void kernel_launch(void* const* d_in, const int* in_sizes, int n_in,
                              void* d_out, int out_size, void* d_ws, size_t ws_size,
                              hipStream_t stream) {
    const float* coords = (const float*)d_in[0];
    const float* grid   = (const float*)d_in[1];
    const float* W1  = (const float*)d_in[2];
    const float* b1  = (const float*)d_in[3];
    const float* g1  = (const float*)d_in[4];
    const float* be1 = (const float*)d_in[5];
    const float* W2  = (const float*)d_in[6];
    const float* b2  = (const float*)d_in[7];
    const float* g2  = (const float*)d_in[8];
    const float* be2 = (const float*)d_in[9];
    const float* W3  = (const float*)d_in[10];
    const float* b3  = (const float*)d_in[11];

    float* gmm_out    = (float*)d_out;                          // N*48 floats
    float* coords_out = (float*)d_out + (size_t)N_PTS * NOUT;   // N*2 floats

    const int nblocks = (N_PTS + BLK - 1) / BLK;
    modgmm_np32_static<<<nblocks, BLK, 0, stream>>>(
        coords, grid, W1, b1, g1, be1, W2, b2, g2, be2, W3, b3,
        gmm_out, coords_out);
}

// Round 9
// 1173.353 us; speedup vs baseline: 2.1221x; 2.1221x over previous
//
#include <hip/hip_runtime.h>
#include <math.h>

// MoDGMMFeatureModel, numpy-fp32-bit-exact (frozen op orders, proven round 3):
//  - sgemm: acc=0, sequential-k __builtin_fmaf, bias added AFTER (own rounding)
//  - LN mean/var: numpy pairwise 8-accumulator pattern, exact sequential m-order
//  - elementwise: contract(off), left-assoc as written
//  - mod: fmodf + conditional += 2pi
// Round 9: WAVE-PAIR j-split. Block = 2 waves over the same 64 points; wave w
// owns the j-half of every layer (64/32/24 outputs) -> acc depth 64 not 128 ->
// ~110 regs -> 4 waves/SIMD (vs R3's 2). Weight addresses stay wave-uniform
// (readfirstlane) -> s_load path preserved. One 16KB LDS buffer X[64][64]
// carries activations between waves in half-phases; all k-loops stay ROLLED
// with hv = ds_read (the only shape the allocator handles without spilling —
// R4/R6/R7/R8 all spilled). amdgpu_waves_per_eu(3,4): min 3 gives a 170-reg
// budget (no forced spill), max 4 stops the allocator shrinking regs to chase
// 8 waves (the R4/R7 spill heuristic).

constexpr int N_PTS = 1000000;
constexpr int GW = 64;
constexpr int FDIM = 32;
constexpr int NH1 = 128;
constexpr int NH2 = 64;
constexpr int NOUT = 48;

__global__ __launch_bounds__(128)
__attribute__((amdgpu_waves_per_eu(3, 4)))
void modgmm_wsplit(
    const float* __restrict__ coords, const float* __restrict__ grid,
    const float* __restrict__ W1, const float* __restrict__ b1,
    const float* __restrict__ g1, const float* __restrict__ be1,
    const float* __restrict__ W2, const float* __restrict__ b2,
    const float* __restrict__ g2, const float* __restrict__ be2,
    const float* __restrict__ W3, const float* __restrict__ b3,
    float* __restrict__ gmm_out, float* __restrict__ coords_out)
{
#pragma clang fp contract(off)
    __shared__ float X[64 * 64];               // [row][pt], 16 KB
    const int p = threadIdx.x & 63;            // point lane
    const int w = __builtin_amdgcn_readfirstlane((int)(threadIdx.x >> 6)); // j-half
    const int gi = blockIdx.x * 64 + p;        // N divides 64 exactly

    float cx = 0.0f, cy = 0.0f;

    // ---- P0: wave 0 gathers f[34] and stages rows 0..33 ----
    if (w == 0) {
        const float2 c2 = reinterpret_cast<const float2*>(coords)[gi];
        cx = c2.x; cy = c2.y;
        const float x = cx * 63.0f;
        const float y = cy * 63.0f;
        int x0 = (int)floorf(x); x0 = x0 < 0 ? 0 : (x0 > 62 ? 62 : x0);
        int y0 = (int)floorf(y); y0 = y0 < 0 ? 0 : (y0 > 62 ? 62 : y0);
        const float dx = x - (float)x0;
        const float dy = y - (float)y0;
        const float omdx = 1.0f - dx;
        const float omdy = 1.0f - dy;
        const float w00 = omdx * omdy;
        const float w01 = omdx * dy;
        const float w10 = dx * omdy;
        const float w11 = dx * dy;
        const float* gp = grid + (y0 * GW + x0) * FDIM;
        const float4* q00 = reinterpret_cast<const float4*>(gp);
        const float4* q01 = reinterpret_cast<const float4*>(gp + GW * FDIM);
        const float4* q10 = reinterpret_cast<const float4*>(gp + FDIM);
        const float4* q11 = reinterpret_cast<const float4*>(gp + GW * FDIM + FDIM);
        X[0 * 64 + p] = cx;
        X[1 * 64 + p] = cy;
#pragma unroll
        for (int e = 0; e < 8; ++e) {
            const float4 a = q00[e], b = q01[e], c = q10[e], d = q11[e];
            const int r0 = 2 + 4 * e;
            { const float t0 = w00*a.x, t1 = w01*b.x, t2 = w10*c.x, t3 = w11*d.x;
              X[(r0+0)*64 + p] = ((t0 + t1) + t2) + t3; }
            { const float t0 = w00*a.y, t1 = w01*b.y, t2 = w10*c.y, t3 = w11*d.y;
              X[(r0+1)*64 + p] = ((t0 + t1) + t2) + t3; }
            { const float t0 = w00*a.z, t1 = w01*b.z, t2 = w10*c.z, t3 = w11*d.z;
              X[(r0+2)*64 + p] = ((t0 + t1) + t2) + t3; }
            { const float t0 = w00*a.w, t1 = w01*b.w, t2 = w10*c.w, t3 = w11*d.w;
              X[(r0+3)*64 + p] = ((t0 + t1) + t2) + t3; }
        }
    }
    __syncthreads();

    // ---- GEMM1: my 64 outputs j in [64w, 64w+64), k = 0..33 sequential ----
    float acc[64];
#pragma unroll
    for (int j = 0; j < 64; ++j) acc[j] = 0.0f;
    {
        const float* Wb = W1 + (w << 6);
        for (int k = 0; k < 34; ++k) {          // rolled
            const float hv = X[k * 64 + p];
            const float* wr = Wb + k * NH1;
#pragma unroll
            for (int q = 0; q < 16; ++q) {
                const float4 wv = *reinterpret_cast<const float4*>(wr + 4 * q);
                acc[4*q+0] = __builtin_fmaf(hv, wv.x, acc[4*q+0]);
                acc[4*q+1] = __builtin_fmaf(hv, wv.y, acc[4*q+1]);
                acc[4*q+2] = __builtin_fmaf(hv, wv.z, acc[4*q+2]);
                acc[4*q+3] = __builtin_fmaf(hv, wv.w, acc[4*q+3]);
            }
        }
    }
    __syncthreads();                            // all f-reads done
    {
        const float* bb = b1 + (w << 6);
#pragma unroll
        for (int j = 0; j < 64; ++j) acc[j] = fmaxf(acc[j] + bb[j], 0.0f);
    }

    // ---- LN1 (n=128): numpy 8-acc pattern, exact m-order via phases ----
    float r[8];
    if (w == 0) {
#pragma unroll
        for (int j = 0; j < 64; ++j) X[j * 64 + p] = acc[j];   // raw0
    }
    __syncthreads();
#pragma unroll
    for (int j = 0; j < 8; ++j) r[j] = X[j * 64 + p];          // m = 0
#pragma unroll
    for (int m = 1; m < 8; ++m)
#pragma unroll
        for (int j = 0; j < 8; ++j) r[j] = r[j] + X[(8 * m + j) * 64 + p];
    __syncthreads();
    if (w == 1) {
#pragma unroll
        for (int j = 0; j < 64; ++j) X[j * 64 + p] = acc[j];   // raw1
    }
    __syncthreads();
#pragma unroll
    for (int m = 8; m < 16; ++m)
#pragma unroll
        for (int j = 0; j < 8; ++j) r[j] = r[j] + X[(8 * m + j - 64) * 64 + p];
    const float mu1 = (((r[0]+r[1]) + (r[2]+r[3])) + ((r[4]+r[5]) + (r[6]+r[7]))) / 128.0f;
    __syncthreads();
    if (w == 0) {
#pragma unroll
        for (int j = 0; j < 64; ++j) X[j * 64 + p] = acc[j];   // raw0 again
    }
    __syncthreads();
#pragma unroll
    for (int j = 0; j < 8; ++j) { const float d = X[j * 64 + p] - mu1; r[j] = d * d; }
#pragma unroll
    for (int m = 1; m < 8; ++m)
#pragma unroll
        for (int j = 0; j < 8; ++j) {
            const float d = X[(8 * m + j) * 64 + p] - mu1;
            r[j] = r[j] + d * d;
        }
    __syncthreads();
    if (w == 1) {
#pragma unroll
        for (int j = 0; j < 64; ++j) X[j * 64 + p] = acc[j];   // raw1 again
    }
    __syncthreads();
#pragma unroll
    for (int m = 8; m < 16; ++m)
#pragma unroll
        for (int j = 0; j < 8; ++j) {
            const float d = X[(8 * m + j - 64) * 64 + p] - mu1;
            r[j] = r[j] + d * d;
        }
    const float var1 = (((r[0]+r[1]) + (r[2]+r[3])) + ((r[4]+r[5]) + (r[6]+r[7]))) / 128.0f;
    const float rs1 = 1.0f / sqrtf(var1 + 1e-5f);
    {
        const float* gg = g1 + (w << 6);
        const float* ee = be1 + (w << 6);
#pragma unroll
        for (int j = 0; j < 64; ++j)
            acc[j] = ((acc[j] - mu1) * rs1) * gg[j] + ee[j];    // norm half
    }

    // ---- GEMM2: my 32 outputs j in [32w, 32w+32), k = 0..127 sequential ----
    float acc2[32];
#pragma unroll
    for (int j = 0; j < 32; ++j) acc2[j] = 0.0f;
    __syncthreads();                            // sq reads done
    if (w == 0) {
#pragma unroll
        for (int j = 0; j < 64; ++j) X[j * 64 + p] = acc[j];   // norm0
    }
    __syncthreads();
    {
        const float* Wb = W2 + (w << 5);
        for (int k = 0; k < 64; ++k) {          // rolled, k = 0..63
            const float hv = X[k * 64 + p];
            const float* wr = Wb + k * NH2;
#pragma unroll
            for (int q = 0; q < 8; ++q) {
                const float4 wv = *reinterpret_cast<const float4*>(wr + 4 * q);
                acc2[4*q+0] = __builtin_fmaf(hv, wv.x, acc2[4*q+0]);
                acc2[4*q+1] = __builtin_fmaf(hv, wv.y, acc2[4*q+1]);
                acc2[4*q+2] = __builtin_fmaf(hv, wv.z, acc2[4*q+2]);
                acc2[4*q+3] = __builtin_fmaf(hv, wv.w, acc2[4*q+3]);
            }
        }
    }
    __syncthreads();
    if (w == 1) {
#pragma unroll
        for (int j = 0; j < 64; ++j) X[j * 64 + p] = acc[j];   // norm1
    }
    __syncthreads();
    {
        const float* Wb = W2 + 64 * NH2 + (w << 5);
        for (int k = 0; k < 64; ++k) {          // rolled, k = 64..127
            const float hv = X[k * 64 + p];
            const float* wr = Wb + k * NH2;
#pragma unroll
            for (int q = 0; q < 8; ++q) {
                const float4 wv = *reinterpret_cast<const float4*>(wr + 4 * q);
                acc2[4*q+0] = __builtin_fmaf(hv, wv.x, acc2[4*q+0]);
                acc2[4*q+1] = __builtin_fmaf(hv, wv.y, acc2[4*q+1]);
                acc2[4*q+2] = __builtin_fmaf(hv, wv.z, acc2[4*q+2]);
                acc2[4*q+3] = __builtin_fmaf(hv, wv.w, acc2[4*q+3]);
            }
        }
    }
    {
        const float* bb = b2 + (w << 5);
#pragma unroll
        for (int j = 0; j < 32; ++j) acc2[j] = fmaxf(acc2[j] + bb[j], 0.0f);
    }

    // ---- LN2 (n=64): 8-acc pattern, m = 0..7, halves split at m=4 ----
    __syncthreads();
    if (w == 0) {
#pragma unroll
        for (int j = 0; j < 32; ++j) X[j * 64 + p] = acc2[j];  // r2_0
    }
    __syncthreads();
#pragma unroll
    for (int j = 0; j < 8; ++j) r[j] = X[j * 64 + p];
#pragma unroll
    for (int m = 1; m < 4; ++m)
#pragma unroll
        for (int j = 0; j < 8; ++j) r[j] = r[j] + X[(8 * m + j) * 64 + p];
    __syncthreads();
    if (w == 1) {
#pragma unroll
        for (int j = 0; j < 32; ++j) X[j * 64 + p] = acc2[j];  // r2_1
    }
    __syncthreads();
#pragma unroll
    for (int m = 4; m < 8; ++m)
#pragma unroll
        for (int j = 0; j < 8; ++j) r[j] = r[j] + X[(8 * m + j - 32) * 64 + p];
    const float mu2 = (((r[0]+r[1]) + (r[2]+r[3])) + ((r[4]+r[5]) + (r[6]+r[7]))) / 64.0f;
    __syncthreads();
    if (w == 0) {
#pragma unroll
        for (int j = 0; j < 32; ++j) X[j * 64 + p] = acc2[j];
    }
    __syncthreads();
#pragma unroll
    for (int j = 0; j < 8; ++j) { const float d = X[j * 64 + p] - mu2; r[j] = d * d; }
#pragma unroll
    for (int m = 1; m < 4; ++m)
#pragma unroll
        for (int j = 0; j < 8; ++j) {
            const float d = X[(8 * m + j) * 64 + p] - mu2;
            r[j] = r[j] + d * d;
        }
    __syncthreads();
    if (w == 1) {
#pragma unroll
        for (int j = 0; j < 32; ++j) X[j * 64 + p] = acc2[j];
    }
    __syncthreads();
#pragma unroll
    for (int m = 4; m < 8; ++m)
#pragma unroll
        for (int j = 0; j < 8; ++j) {
            const float d = X[(8 * m + j - 32) * 64 + p] - mu2;
            r[j] = r[j] + d * d;
        }
    const float var2 = (((r[0]+r[1]) + (r[2]+r[3])) + ((r[4]+r[5]) + (r[6]+r[7]))) / 64.0f;
    const float rs2 = 1.0f / sqrtf(var2 + 1e-5f);
    {
        const float* gg = g2 + (w << 5);
        const float* ee = be2 + (w << 5);
#pragma unroll
        for (int j = 0; j < 32; ++j)
            acc2[j] = ((acc2[j] - mu2) * rs2) * gg[j] + ee[j];  // n2 half
    }

    // ---- GEMM3: my 24 outputs j in [24w, 24w+24), k = 0..63 sequential ----
    float o[24];
#pragma unroll
    for (int j = 0; j < 24; ++j) o[j] = 0.0f;
    __syncthreads();
    if (w == 0) {
#pragma unroll
        for (int j = 0; j < 32; ++j) X[j * 64 + p] = acc2[j];  // n2_0
    }
    __syncthreads();
    {
        const float* Wb = W3 + 24 * w;
        for (int k = 0; k < 32; ++k) {          // rolled, k = 0..31
            const float hv = X[k * 64 + p];
            const float* wr = Wb + k * NOUT;
#pragma unroll
            for (int q = 0; q < 6; ++q) {
                const float4 wv = *reinterpret_cast<const float4*>(wr + 4 * q);
                o[4*q+0] = __builtin_fmaf(hv, wv.x, o[4*q+0]);
                o[4*q+1] = __builtin_fmaf(hv, wv.y, o[4*q+1]);
                o[4*q+2] = __builtin_fmaf(hv, wv.z, o[4*q+2]);
                o[4*q+3] = __builtin_fmaf(hv, wv.w, o[4*q+3]);
            }
        }
    }
    __syncthreads();
    if (w == 1) {
#pragma unroll
        for (int j = 0; j < 32; ++j) X[j * 64 + p] = acc2[j];  // n2_1
    }
    __syncthreads();
    {
        const float* Wb = W3 + 32 * NOUT + 24 * w;
        for (int k = 0; k < 32; ++k) {          // rolled, k = 32..63
            const float hv = X[k * 64 + p];
            const float* wr = Wb + k * NOUT;
#pragma unroll
            for (int q = 0; q < 6; ++q) {
                const float4 wv = *reinterpret_cast<const float4*>(wr + 4 * q);
                o[4*q+0] = __builtin_fmaf(hv, wv.x, o[4*q+0]);
                o[4*q+1] = __builtin_fmaf(hv, wv.y, o[4*q+1]);
                o[4*q+2] = __builtin_fmaf(hv, wv.z, o[4*q+2]);
                o[4*q+3] = __builtin_fmaf(hv, wv.w, o[4*q+3]);
            }
        }
    }
    {
        const float* bb = b3 + 24 * w;
#pragma unroll
        for (int j = 0; j < 24; ++j) o[j] = o[j] + bb[j];
    }

    // ---- GMM postprocess: my comps c = 4w..4w+3 ----
    const float TPf = 6.28318530717958647692f;
    // global max: max is exactly associative -> any grouping matches the
    // reference's sequential fold bitwise
    const float lm = fmaxf(fmaxf(fmaxf(o[0], o[6]), o[12]), o[18]);
    __syncthreads();                   // X free (all GEMM3 reads done)
    X[w * 64 + p] = lm;
    __syncthreads();
    const float mm = fmaxf(lm, X[(1 - w) * 64 + p]);
    float e[4];
#pragma unroll
    for (int cl = 0; cl < 4; ++cl) e[cl] = expf(o[6 * cl] - mm);
    const float qq = (e[0] + e[1]) + (e[2] + e[3]);   // my quad of the esum tree
    X[(2 + w) * 64 + p] = qq;
    __syncthreads();
    const float qo = X[(3 - w) * 64 + p];
    const float esum = (w == 0) ? (qq + qo) : (qo + qq);   // q0 + q1 both ways

    float res[24];
#pragma unroll
    for (int cl = 0; cl < 4; ++cl) {
        const int off = 6 * cl;
        res[off + 0] = e[cl] / esum;
        res[off + 1] = fmaxf(o[off + 1], 0.0f);
        float a = fmodf(o[off + 2], TPf);
        if (a < 0.0f) a += TPf;
        res[off + 2] = a;
        res[off + 3] = expf(fminf(fmaxf(o[off + 3], -10.0f), 10.0f));
        res[off + 4] = expf(fminf(fmaxf(o[off + 4], -10.0f), 10.0f));
        res[off + 5] = 0.99f * tanhf(o[off + 5]);
    }

    // ---- stores: 96 B contiguous per thread; halves meet at 64B lines in L2 ----
    float4* og = reinterpret_cast<float4*>(gmm_out + (size_t)gi * NOUT + 24 * w);
#pragma unroll
    for (int q = 0; q < 6; ++q)
        og[q] = make_float4(res[4 * q + 0], res[4 * q + 1], res[4 * q + 2], res[4 * q + 3]);
    if (w == 0)
        reinterpret_cast<float2*>(coords_out)[gi] = make_float2(cx, cy);
}

extern "C" void kernel_launch(void* const* d_in, const int* in_sizes, int n_in,
                              void* d_out, int out_size, void* d_ws, size_t ws_size,
                              hipStream_t stream) {
    const float* coords = (const float*)d_in[0];
    const float* grid   = (const float*)d_in[1];
    const float* W1  = (const float*)d_in[2];
    const float* b1  = (const float*)d_in[3];
    const float* g1  = (const float*)d_in[4];
    const float* be1 = (const float*)d_in[5];
    const float* W2  = (const float*)d_in[6];
    const float* b2  = (const float*)d_in[7];
    const float* g2  = (const float*)d_in[8];
    const float* be2 = (const float*)d_in[9];
    const float* W3  = (const float*)d_in[10];
    const float* b3  = (const float*)d_in[11];

    float* gmm_out    = (float*)d_out;                          // N*48 floats
    float* coords_out = (float*)d_out + (size_t)N_PTS * NOUT;   // N*2 floats

    const int nblocks = N_PTS / 64;    // 15625, exact
    modgmm_wsplit<<<nblocks, 128, 0, stream>>>(
        coords, grid, W1, b1, g1, be1, W2, b2, g2, be2, W3, b3,
        gmm_out, coords_out);
}